// Round 6
// baseline (245.454 us; speedup 1.0000x reference)
//
#include <hip/hip_runtime.h>
#include <math.h>

#define BATCH    2
#define SEQ      2048
#define DIM      1024
#define HEADS    16
#define HEAD_DIM 64
#define K_NEI    64
#define QKV_DIM  3072
#define MROWS    (BATCH * SEQ)   // 4096
#define ATT_SCALE 0.125f

typedef _Float16 half8  __attribute__((ext_vector_type(8)));
typedef _Float16 half4  __attribute__((ext_vector_type(4)));
typedef float    floatx4 __attribute__((ext_vector_type(4)));

__device__ inline void async_copy16(const void* g, void* l) {
  __builtin_amdgcn_global_load_lds(
      (const __attribute__((address_space(1))) unsigned int*)g,
      (__attribute__((address_space(3))) unsigned int*)l, 16, 0, 0);
}

// fused fp32 -> f16 cast of three tensors (sizes in float4 groups)
__global__ __launch_bounds__(256)
void cast3(const float* __restrict__ a, int na4,
           const float* __restrict__ b, int nb4,
           const float* __restrict__ c, int nc4,
           _Float16* __restrict__ oa, _Float16* __restrict__ ob,
           _Float16* __restrict__ oc) {
  const int total = na4 + nb4 + nc4;
  for (int i = blockIdx.x * blockDim.x + threadIdx.x; i < total;
       i += gridDim.x * blockDim.x) {
    const float* src; _Float16* dst; int idx;
    if (i < na4)            { src = a; dst = oa; idx = i; }
    else if (i < na4 + nb4) { src = b; dst = ob; idx = i - na4; }
    else                    { src = c; dst = oc; idx = i - na4 - nb4; }
    float4 v = *(const float4*)(src + (size_t)idx * 4);
    half4 o;
    o[0] = (_Float16)v.x; o[1] = (_Float16)v.y;
    o[2] = (_Float16)v.z; o[3] = (_Float16)v.w;
    *(half4*)(dst + (size_t)idx * 4) = o;
  }
}

// C[m,n] = sum_k A[m,k]*B[n,k] + bias[n]; A:[M,K] f16, B:[N,K] f16.
template<bool HALF_OUT>
__global__ __launch_bounds__(256)
void gemm_bt_f16(const _Float16* __restrict__ A, const _Float16* __restrict__ B,
                 const float* __restrict__ bias, void* __restrict__ Cv,
                 int M, int N, int K) {
  __shared__ _Float16 As[128 * 32];   // 8 KB
  __shared__ _Float16 Bs[128 * 32];

  const int tid  = threadIdx.x;
  const int lane = tid & 63;
  const int w    = tid >> 6;
  const int wr   = w >> 1;
  const int wc   = w & 1;
  const int bm   = blockIdx.y * 128;
  const int bn   = blockIdx.x * 128;

  const int srow = w * 32 + (lane >> 2);
  const int scol = (lane & 3) * 8;
  const _Float16* ga = A + (size_t)(bm + srow) * K + scol;
  const _Float16* gb = B + (size_t)(bn + srow) * K + scol;
  _Float16* la = As + (w * 32) * 32;
  _Float16* lb = Bs + (w * 32) * 32;

  const int frow = lane & 15;
  const int fk   = (lane >> 4) * 8;

  floatx4 acc[4][4] = {};

  for (int k0 = 0; k0 < K; k0 += 32) {
    async_copy16(ga + k0,          la);
    async_copy16(ga + k0 + 16 * K, la + 16 * 32);
    async_copy16(gb + k0,          lb);
    async_copy16(gb + k0 + 16 * K, lb + 16 * 32);
    __syncthreads();

    half8 af[4], bf[4];
#pragma unroll
    for (int i = 0; i < 4; i++)
      af[i] = *(const half8*)&As[(wr * 64 + i * 16 + frow) * 32 + fk];
#pragma unroll
    for (int j = 0; j < 4; j++)
      bf[j] = *(const half8*)&Bs[(wc * 64 + j * 16 + frow) * 32 + fk];
#pragma unroll
    for (int i = 0; i < 4; i++)
#pragma unroll
      for (int j = 0; j < 4; j++) {
        if (HALF_OUT)
          acc[i][j] = __builtin_amdgcn_mfma_f32_16x16x32_f16(bf[j], af[i], acc[i][j], 0, 0, 0);
        else
          acc[i][j] = __builtin_amdgcn_mfma_f32_16x16x32_f16(af[i], bf[j], acc[i][j], 0, 0, 0);
      }
    __syncthreads();
  }

  if (HALF_OUT) {
    _Float16* C = (_Float16*)Cv;
    const int mloc = lane & 15;
    const int nloc = (lane >> 4) * 4;
#pragma unroll
    for (int j = 0; j < 4; j++) {
      const int gcol = bn + wc * 64 + j * 16 + nloc;
      float4 bj = *(const float4*)(bias + gcol);
#pragma unroll
      for (int i = 0; i < 4; i++) {
        const int grow = bm + wr * 64 + i * 16 + mloc;
        half4 hv;
        hv[0] = (_Float16)(acc[i][j][0] + bj.x);
        hv[1] = (_Float16)(acc[i][j][1] + bj.y);
        hv[2] = (_Float16)(acc[i][j][2] + bj.z);
        hv[3] = (_Float16)(acc[i][j][3] + bj.w);
        *(half4*)(C + (size_t)grow * N + gcol) = hv;
      }
    }
  } else {
    float* C = (float*)Cv;
    const int crow = (lane >> 4) * 4;
    const int ccol = lane & 15;
#pragma unroll
    for (int j = 0; j < 4; j++) {
      const int gcol = bn + wc * 64 + j * 16 + ccol;
      const float bj = bias[gcol];
#pragma unroll
      for (int i = 0; i < 4; i++) {
        const int grow = bm + wr * 64 + i * 16 + crow;
        float* cp = C + (size_t)grow * N + gcol;
#pragma unroll
        for (int r = 0; r < 4; r++)
          cp[(size_t)r * N] = acc[i][j][r] + bj;
      }
    }
  }
}

// MFMA-score gathered attention. One (b,h,q) per wave, 4 waves/block.
// Scores: 64x64 K-gather x q matvec via 8 mfma_f32_16x16x32_f16 (q replicated
// into all 16 B-columns). V: quad-cooperative 8B loads parked in registers
// (independent of softmax). p crosses score->V layout via 1KB/block LDS
// (wave-synchronous, no barriers).
__global__ __launch_bounds__(256, 4)
void attn_kernel(const _Float16* __restrict__ qkv,
                 const int* __restrict__ routes,
                 _Float16* __restrict__ ao) {
  const int lane = threadIdx.x & 63;
  const int w    = threadIdx.x >> 6;
  const int g    = lane >> 4;          // group 0..3
  const int c    = lane & 15;          // chunk / column id within group

  const int i    = blockIdx.x;          // 0..16383
  const int xcd  = i & 7;
  const int j    = i >> 3;
  const int bh   = j >> 6;
  const int qsub = j & 63;
  const int qblk = xcd * 64 + qsub;
  const int q    = qblk * 4 + w;
  const int h    = bh & 15;
  const int b    = bh >> 4;

  __shared__ float pshared[4][64];

  const size_t row_base = (size_t)b * SEQ;
  const int    hoff     = h * HEAD_DIM;

  const int rt = routes[q * K_NEI + lane];   // lane r holds route[r]

  // q fragments (B-operand, replicated over columns): octet by group g
  const _Float16* qrow = qkv + (row_base + q) * QKV_DIM + hoff;
  const half8 qa = *(const half8*)(qrow + 8 * g);        // dims [8g, 8g+8)
  const half8 qb = *(const half8*)(qrow + 32 + 8 * g);   // dims [32+8g, ...)

  // ---- V prefetch (independent of scores): pass t loads row route[4t+g],
  //      16 lanes x 8B contiguous -> 4 x 128B segments per instruction ----
  half4 vv[16];
#pragma unroll
  for (int t = 0; t < 16; t++) {
    const int vr = __shfl(rt, 4 * t + g);
    vv[t] = *(const half4*)(qkv + (row_base + vr) * QKV_DIM + 2 * DIM + hoff + 4 * c);
  }

  // ---- scores via MFMA: tile t = neighbors [16t,16t+16) ----
  floatx4 acc[4];
#pragma unroll
  for (int t = 0; t < 4; t++) {
    const int ri = __shfl(rt, 16 * t + c);   // A-frag row m = c
    const _Float16* kp = qkv + (row_base + ri) * QKV_DIM + DIM + hoff;
    half8 ka = *(const half8*)(kp + 8 * g);
    half8 kb = *(const half8*)(kp + 32 + 8 * g);
    floatx4 z = {0.f, 0.f, 0.f, 0.f};
    z = __builtin_amdgcn_mfma_f32_16x16x32_f16(ka, qa, z, 0, 0, 0);
    acc[t] = __builtin_amdgcn_mfma_f32_16x16x32_f16(kb, qb, z, 0, 0, 0);
  }
  // lane now holds score[16t + 4g + r] in acc[t][r] (replicated over c)

  // ---- softmax over 64 scores ----
  float m = acc[0][0];
#pragma unroll
  for (int t = 0; t < 4; t++)
#pragma unroll
    for (int r = 0; r < 4; r++) m = fmaxf(m, acc[t][r]);
  m = fmaxf(m, __shfl_xor(m, 16));
  m = fmaxf(m, __shfl_xor(m, 32));

  float pe[4][4];
  float sum = 0.f;
#pragma unroll
  for (int t = 0; t < 4; t++)
#pragma unroll
    for (int r = 0; r < 4; r++) {
      pe[t][r] = __expf((acc[t][r] - m) * ATT_SCALE);
      sum += pe[t][r];
    }
  sum += __shfl_xor(sum, 16);
  sum += __shfl_xor(sum, 32);
  const float rinv = 1.f / sum;

  // ---- p: score layout -> V layout via per-wave LDS (wave-synchronous) ----
  if (c == 0) {
#pragma unroll
    for (int t = 0; t < 4; t++)
#pragma unroll
      for (int r = 0; r < 4; r++)
        pshared[w][16 * t + 4 * g + r] = pe[t][r] * rinv;
  }

  // ---- weighted V sum (memory already in registers) ----
  float o0 = 0.f, o1 = 0.f, o2 = 0.f, o3 = 0.f;
#pragma unroll
  for (int t = 0; t < 16; t++) {
    const float p = pshared[w][4 * t + g];
    o0 += p * (float)vv[t][0];
    o1 += p * (float)vv[t][1];
    o2 += p * (float)vv[t][2];
    o3 += p * (float)vv[t][3];
  }
  o0 += __shfl_xor(o0, 16); o0 += __shfl_xor(o0, 32);
  o1 += __shfl_xor(o1, 16); o1 += __shfl_xor(o1, 32);
  o2 += __shfl_xor(o2, 16); o2 += __shfl_xor(o2, 32);
  o3 += __shfl_xor(o3, 16); o3 += __shfl_xor(o3, 32);

  if (g == 0) {
    half4 hv;
    hv[0] = (_Float16)o0; hv[1] = (_Float16)o1;
    hv[2] = (_Float16)o2; hv[3] = (_Float16)o3;
    *(half4*)(ao + (row_base + q) * DIM + hoff + 4 * c) = hv;
  }
}

extern "C" void kernel_launch(void* const* d_in, const int* in_sizes, int n_in,
                              void* d_out, int out_size, void* d_ws, size_t ws_size,
                              hipStream_t stream) {
  const float* x      = (const float*)d_in[0];
  const int*   routes = (const int*)  d_in[1];
  const float* qkv_w  = (const float*)d_in[2];
  const float* qkv_b  = (const float*)d_in[3];
  const float* out_w  = (const float*)d_in[4];
  const float* out_b  = (const float*)d_in[5];
  float* out = (float*)d_out;

  _Float16* qkvh = (_Float16*)d_ws;                       // 4096*3072
  _Float16* aoh  = qkvh + (size_t)MROWS * QKV_DIM;        // 4096*1024
  _Float16* xh   = aoh  + (size_t)MROWS * DIM;            // 4096*1024
  _Float16* wh   = xh   + (size_t)MROWS * DIM;            // 3072*1024
  _Float16* owh  = wh   + (size_t)QKV_DIM * DIM;          // 1024*1024

  cast3<<<1024, 256, 0, stream>>>(x, MROWS * DIM / 4,
                                  qkv_w, QKV_DIM * DIM / 4,
                                  out_w, DIM * DIM / 4,
                                  xh, wh, owh);

  {
    dim3 g(QKV_DIM / 128, MROWS / 128);
    gemm_bt_f16<true><<<g, 256, 0, stream>>>(xh, wh, qkv_b, qkvh,
                                             MROWS, QKV_DIM, DIM);
  }

  attn_kernel<<<(BATCH * HEADS * SEQ) / 4, 256, 0, stream>>>(qkvh, routes, aoh);

  {
    dim3 g(DIM / 128, MROWS / 128);
    gemm_bt_f16<false><<<g, 256, 0, stream>>>(aoh, owh, out_b, out,
                                              MROWS, DIM, DIM);
  }
}

// Round 7
// 211.283 us; speedup vs baseline: 1.1617x; 1.1617x over previous
//
#include <hip/hip_runtime.h>
#include <math.h>

#define BATCH    2
#define SEQ      2048
#define DIM      1024
#define HEADS    16
#define HEAD_DIM 64
#define K_NEI    64
#define QKV_DIM  3072
#define MROWS    (BATCH * SEQ)   // 4096
#define ATT_SCALE 0.125f

typedef _Float16 half8  __attribute__((ext_vector_type(8)));
typedef _Float16 half4  __attribute__((ext_vector_type(4)));
typedef _Float16 half2t __attribute__((ext_vector_type(2)));
typedef float    floatx4 __attribute__((ext_vector_type(4)));

__device__ inline void async_copy16(const void* g, void* l) {
  __builtin_amdgcn_global_load_lds(
      (const __attribute__((address_space(1))) unsigned int*)g,
      (__attribute__((address_space(3))) unsigned int*)l, 16, 0, 0);
}

__device__ inline float dot2h(half2t a, half2t b, float c) {
#if defined(__has_builtin) && __has_builtin(__builtin_amdgcn_fdot2)
  return __builtin_amdgcn_fdot2(a, b, c, false);
#else
  return c + (float)a[0] * (float)b[0] + (float)a[1] * (float)b[1];
#endif
}

// fused fp32 -> f16 cast of three tensors (sizes in float4 groups)
__global__ __launch_bounds__(256)
void cast3(const float* __restrict__ a, int na4,
           const float* __restrict__ b, int nb4,
           const float* __restrict__ c, int nc4,
           _Float16* __restrict__ oa, _Float16* __restrict__ ob,
           _Float16* __restrict__ oc) {
  const int total = na4 + nb4 + nc4;
  for (int i = blockIdx.x * blockDim.x + threadIdx.x; i < total;
       i += gridDim.x * blockDim.x) {
    const float* src; _Float16* dst; int idx;
    if (i < na4)            { src = a; dst = oa; idx = i; }
    else if (i < na4 + nb4) { src = b; dst = ob; idx = i - na4; }
    else                    { src = c; dst = oc; idx = i - na4 - nb4; }
    float4 v = *(const float4*)(src + (size_t)idx * 4);
    half4 o;
    o[0] = (_Float16)v.x; o[1] = (_Float16)v.y;
    o[2] = (_Float16)v.z; o[3] = (_Float16)v.w;
    *(half4*)(dst + (size_t)idx * 4) = o;
  }
}

// C[m,n] = sum_k A[m,k]*B[n,k] + bias[n]; A:[M,K] f16, B:[N,K] f16.
// BK=64 as two 32-wide sub-tiles staged together -> one barrier pair / 64 K.
// Wave grid 2x2; per-wave frags (BM/32)x(BN/32) of 16x16x32 MFMA.
template<int BM, int BN, bool HALF_OUT>
__global__ __launch_bounds__(256)
void gemm_bt_f16(const _Float16* __restrict__ A, const _Float16* __restrict__ B,
                 const float* __restrict__ bias, void* __restrict__ Cv,
                 int M, int N, int K) {
  constexpr int FI = BM / 32;
  constexpr int FJ = BN / 32;
  constexpr int CA = BM / 64;   // global_load_lds instrs per thread per sub-tile
  constexpr int CB = BN / 64;
  __shared__ _Float16 As[2 * BM * 32];
  __shared__ _Float16 Bs[2 * BN * 32];

  const int tid  = threadIdx.x;
  const int lane = tid & 63;
  const int w    = tid >> 6;
  const int wr   = w >> 1;
  const int wc   = w & 1;
  const int bm   = blockIdx.y * BM;
  const int bn   = blockIdx.x * BN;

  // staging: chunk = w*64 + i*256 + lane; row = chunk>>2; col8 = (chunk&3)*8
  const int srow = w * 16 + (lane >> 2);
  const int scol = (lane & 3) * 8;
  const _Float16* ga = A + (size_t)(bm + srow) * K + scol;
  const _Float16* gb = B + (size_t)(bn + srow) * K + scol;

  const int frow = lane & 15;
  const int fk   = (lane >> 4) * 8;

  floatx4 acc[FI][FJ] = {};

  for (int k0 = 0; k0 < K; k0 += 64) {
#pragma unroll
    for (int sub = 0; sub < 2; sub++) {
      const int kk = k0 + sub * 32;
#pragma unroll
      for (int i = 0; i < CA; i++)
        async_copy16(ga + (size_t)(i * 64) * K + kk,
                     As + sub * BM * 32 + w * 512 + i * 2048);
#pragma unroll
      for (int i = 0; i < CB; i++)
        async_copy16(gb + (size_t)(i * 64) * K + kk,
                     Bs + sub * BN * 32 + w * 512 + i * 2048);
    }
    __syncthreads();

#pragma unroll
    for (int sub = 0; sub < 2; sub++) {
      half8 af[FI], bf[FJ];
#pragma unroll
      for (int i = 0; i < FI; i++)
        af[i] = *(const half8*)&As[sub * BM * 32 + (wr * (BM / 2) + i * 16 + frow) * 32 + fk];
#pragma unroll
      for (int j = 0; j < FJ; j++)
        bf[j] = *(const half8*)&Bs[sub * BN * 32 + (wc * (BN / 2) + j * 16 + frow) * 32 + fk];
#pragma unroll
      for (int i = 0; i < FI; i++)
#pragma unroll
        for (int j = 0; j < FJ; j++) {
          if (HALF_OUT)
            acc[i][j] = __builtin_amdgcn_mfma_f32_16x16x32_f16(bf[j], af[i], acc[i][j], 0, 0, 0);
          else
            acc[i][j] = __builtin_amdgcn_mfma_f32_16x16x32_f16(af[i], bf[j], acc[i][j], 0, 0, 0);
        }
    }
    __syncthreads();
  }

  if (HALF_OUT) {
    _Float16* C = (_Float16*)Cv;
    const int mloc = lane & 15;
    const int nloc = (lane >> 4) * 4;
#pragma unroll
    for (int j = 0; j < FJ; j++) {
      const int gcol = bn + wc * (BN / 2) + j * 16 + nloc;
      float4 bj = *(const float4*)(bias + gcol);
#pragma unroll
      for (int i = 0; i < FI; i++) {
        const int grow = bm + wr * (BM / 2) + i * 16 + mloc;
        half4 hv;
        hv[0] = (_Float16)(acc[i][j][0] + bj.x);
        hv[1] = (_Float16)(acc[i][j][1] + bj.y);
        hv[2] = (_Float16)(acc[i][j][2] + bj.z);
        hv[3] = (_Float16)(acc[i][j][3] + bj.w);
        *(half4*)(C + (size_t)grow * N + gcol) = hv;
      }
    }
  } else {
    float* C = (float*)Cv;
    const int crow = (lane >> 4) * 4;
    const int ccol = lane & 15;
#pragma unroll
    for (int j = 0; j < FJ; j++) {
      const int gcol = bn + wc * (BN / 2) + j * 16 + ccol;
      const float bj = bias[gcol];
#pragma unroll
      for (int i = 0; i < FI; i++) {
        const int grow = bm + wr * (BM / 2) + i * 16 + crow;
        float* cp = C + (size_t)grow * N + gcol;
#pragma unroll
        for (int r = 0; r < 4; r++)
          cp[(size_t)r * N] = acc[i][j][r] + bj;
      }
    }
  }
}

// Quad-cooperative gathered attention (round-5 version, measured 81.7 us).
// Lane l = (group g = l>>4, chunk c = l&15). Pass t: group g loads K/V row
// routes[4t+g] as 16x8B contiguous (4x128B segments per instruction).
// V rows parked in registers during score phase. Zero LDS, zero barriers.
__global__ __launch_bounds__(256, 4)
void attn_kernel(const _Float16* __restrict__ qkv,
                 const int* __restrict__ routes,
                 _Float16* __restrict__ ao) {
  const int lane = threadIdx.x & 63;
  const int w    = threadIdx.x >> 6;
  const int g    = lane >> 4;          // row group 0..3
  const int c    = lane & 15;          // 8B chunk within row

  const int i    = blockIdx.x;          // 0..16383
  const int xcd  = i & 7;
  const int j    = i >> 3;
  const int bh   = j >> 6;
  const int qsub = j & 63;
  const int qblk = xcd * 64 + qsub;
  const int q    = qblk * 4 + w;
  const int h    = bh & 15;
  const int b    = bh >> 4;

  const size_t row_base = (size_t)b * SEQ;
  const int    hoff     = h * HEAD_DIM;

  const int rt = routes[q * K_NEI + lane];

  const half4 qv = *(const half4*)(qkv + (row_base + q) * QKV_DIM + hoff + 4 * c);
  const half2t qv01 = { qv[0], qv[1] };
  const half2t qv23 = { qv[2], qv[3] };

  float  s_reg[16];
  half4  vv[16];

#pragma unroll
  for (int t = 0; t < 16; t++) {
    const int ri = __shfl(rt, 4 * t + g);
    const _Float16* kp = qkv + (row_base + ri) * QKV_DIM + DIM + hoff + 4 * c;
    half4 kv = *(const half4*)kp;
    vv[t]    = *(const half4*)(kp + DIM);
    half2t k01 = { kv[0], kv[1] };
    half2t k23 = { kv[2], kv[3] };
    float sp = dot2h(k23, qv23, dot2h(k01, qv01, 0.f));
#pragma unroll
    for (int off = 1; off < 16; off <<= 1) sp += __shfl_xor(sp, off);
    s_reg[t] = sp;
  }

  float m = s_reg[0];
#pragma unroll
  for (int t = 1; t < 16; t++) m = fmaxf(m, s_reg[t]);
  m = fmaxf(m, __shfl_xor(m, 16));
  m = fmaxf(m, __shfl_xor(m, 32));

  float sum = 0.f;
#pragma unroll
  for (int t = 0; t < 16; t++) {
    s_reg[t] = __expf((s_reg[t] - m) * ATT_SCALE);
    sum += s_reg[t];
  }
  sum += __shfl_xor(sum, 16);
  sum += __shfl_xor(sum, 32);
  const float rinv = 1.f / sum;

  float o0 = 0.f, o1 = 0.f, o2 = 0.f, o3 = 0.f;
#pragma unroll
  for (int t = 0; t < 16; t++) {
    const float p = s_reg[t] * rinv;
    o0 += p * (float)vv[t][0];
    o1 += p * (float)vv[t][1];
    o2 += p * (float)vv[t][2];
    o3 += p * (float)vv[t][3];
  }
  o0 += __shfl_xor(o0, 16); o0 += __shfl_xor(o0, 32);
  o1 += __shfl_xor(o1, 16); o1 += __shfl_xor(o1, 32);
  o2 += __shfl_xor(o2, 16); o2 += __shfl_xor(o2, 32);
  o3 += __shfl_xor(o3, 16); o3 += __shfl_xor(o3, 32);

  if (g == 0) {
    half4 hv;
    hv[0] = (_Float16)o0; hv[1] = (_Float16)o1;
    hv[2] = (_Float16)o2; hv[3] = (_Float16)o3;
    *(half4*)(ao + (row_base + q) * DIM + hoff + 4 * c) = hv;
  }
}

extern "C" void kernel_launch(void* const* d_in, const int* in_sizes, int n_in,
                              void* d_out, int out_size, void* d_ws, size_t ws_size,
                              hipStream_t stream) {
  const float* x      = (const float*)d_in[0];
  const int*   routes = (const int*)  d_in[1];
  const float* qkv_w  = (const float*)d_in[2];
  const float* qkv_b  = (const float*)d_in[3];
  const float* out_w  = (const float*)d_in[4];
  const float* out_b  = (const float*)d_in[5];
  float* out = (float*)d_out;

  _Float16* qkvh = (_Float16*)d_ws;                       // 4096*3072
  _Float16* aoh  = qkvh + (size_t)MROWS * QKV_DIM;        // 4096*1024
  _Float16* xh   = aoh  + (size_t)MROWS * DIM;            // 4096*1024
  _Float16* wh   = xh   + (size_t)MROWS * DIM;            // 3072*1024
  _Float16* owh  = wh   + (size_t)QKV_DIM * DIM;          // 1024*1024

  cast3<<<1024, 256, 0, stream>>>(x, MROWS * DIM / 4,
                                  qkv_w, QKV_DIM * DIM / 4,
                                  out_w, DIM * DIM / 4,
                                  xh, wh, owh);

  // QKV projection: 128x128 tile, 768 blocks
  {
    dim3 g(QKV_DIM / 128, MROWS / 128);
    gemm_bt_f16<128, 128, true><<<g, 256, 0, stream>>>(xh, wh, qkv_b, qkvh,
                                                       MROWS, QKV_DIM, DIM);
  }

  attn_kernel<<<(BATCH * HEADS * SEQ) / 4, 256, 0, stream>>>(qkvh, routes, aoh);

  // output projection: 64x128 tile -> 512 blocks (was 256 = 1/CU, no hiding)
  {
    dim3 g(DIM / 128, MROWS / 64);
    gemm_bt_f16<64, 128, false><<<g, 256, 0, stream>>>(aoh, owh, out_b, out,
                                                       MROWS, DIM, DIM);
  }
}

// Round 8
// 209.889 us; speedup vs baseline: 1.1694x; 1.0066x over previous
//
#include <hip/hip_runtime.h>
#include <math.h>

#define BATCH    2
#define SEQ      2048
#define DIM      1024
#define HEADS    16
#define HEAD_DIM 64
#define K_NEI    64
#define QKV_DIM  3072
#define MROWS    (BATCH * SEQ)   // 4096
#define ATT_SCALE 0.125f

typedef _Float16 half8  __attribute__((ext_vector_type(8)));
typedef _Float16 half4  __attribute__((ext_vector_type(4)));
typedef _Float16 half2t __attribute__((ext_vector_type(2)));
typedef float    floatx4 __attribute__((ext_vector_type(4)));

__device__ inline void async_copy16(const void* g, void* l) {
  __builtin_amdgcn_global_load_lds(
      (const __attribute__((address_space(1))) unsigned int*)g,
      (__attribute__((address_space(3))) unsigned int*)l, 16, 0, 0);
}

__device__ inline float dot2h(half2t a, half2t b, float c) {
#if defined(__has_builtin) && __has_builtin(__builtin_amdgcn_fdot2)
  return __builtin_amdgcn_fdot2(a, b, c, false);
#else
  return c + (float)a[0] * (float)b[0] + (float)a[1] * (float)b[1];
#endif
}

// fused fp32 -> f16 cast of three tensors (sizes in float4 groups)
__global__ __launch_bounds__(256)
void cast3(const float* __restrict__ a, int na4,
           const float* __restrict__ b, int nb4,
           const float* __restrict__ c, int nc4,
           _Float16* __restrict__ oa, _Float16* __restrict__ ob,
           _Float16* __restrict__ oc) {
  const int total = na4 + nb4 + nc4;
  for (int i = blockIdx.x * blockDim.x + threadIdx.x; i < total;
       i += gridDim.x * blockDim.x) {
    const float* src; _Float16* dst; int idx;
    if (i < na4)            { src = a; dst = oa; idx = i; }
    else if (i < na4 + nb4) { src = b; dst = ob; idx = i - na4; }
    else                    { src = c; dst = oc; idx = i - na4 - nb4; }
    float4 v = *(const float4*)(src + (size_t)idx * 4);
    half4 o;
    o[0] = (_Float16)v.x; o[1] = (_Float16)v.y;
    o[2] = (_Float16)v.z; o[3] = (_Float16)v.w;
    *(half4*)(dst + (size_t)idx * 4) = o;
  }
}

// C[m,n] = sum_k A[m,k]*B[n,k] + bias[n]; A:[M,K] f16, B:[N,K] f16.
// BK=64 as two 32-wide sub-tiles staged together -> one barrier pair / 64 K.
template<int BM, int BN, bool HALF_OUT>
__global__ __launch_bounds__(256)
void gemm_bt_f16(const _Float16* __restrict__ A, const _Float16* __restrict__ B,
                 const float* __restrict__ bias, void* __restrict__ Cv,
                 int M, int N, int K) {
  constexpr int FI = BM / 32;
  constexpr int FJ = BN / 32;
  constexpr int CA = BM / 64;
  constexpr int CB = BN / 64;
  __shared__ _Float16 As[2 * BM * 32];
  __shared__ _Float16 Bs[2 * BN * 32];

  const int tid  = threadIdx.x;
  const int lane = tid & 63;
  const int w    = tid >> 6;
  const int wr   = w >> 1;
  const int wc   = w & 1;
  const int bm   = blockIdx.y * BM;
  const int bn   = blockIdx.x * BN;

  const int srow = w * 16 + (lane >> 2);
  const int scol = (lane & 3) * 8;
  const _Float16* ga = A + (size_t)(bm + srow) * K + scol;
  const _Float16* gb = B + (size_t)(bn + srow) * K + scol;

  const int frow = lane & 15;
  const int fk   = (lane >> 4) * 8;

  floatx4 acc[FI][FJ] = {};

  for (int k0 = 0; k0 < K; k0 += 64) {
#pragma unroll
    for (int sub = 0; sub < 2; sub++) {
      const int kk = k0 + sub * 32;
#pragma unroll
      for (int i = 0; i < CA; i++)
        async_copy16(ga + (size_t)(i * 64) * K + kk,
                     As + sub * BM * 32 + w * 512 + i * 2048);
#pragma unroll
      for (int i = 0; i < CB; i++)
        async_copy16(gb + (size_t)(i * 64) * K + kk,
                     Bs + sub * BN * 32 + w * 512 + i * 2048);
    }
    __syncthreads();

#pragma unroll
    for (int sub = 0; sub < 2; sub++) {
      half8 af[FI], bf[FJ];
#pragma unroll
      for (int i = 0; i < FI; i++)
        af[i] = *(const half8*)&As[sub * BM * 32 + (wr * (BM / 2) + i * 16 + frow) * 32 + fk];
#pragma unroll
      for (int j = 0; j < FJ; j++)
        bf[j] = *(const half8*)&Bs[sub * BN * 32 + (wc * (BN / 2) + j * 16 + frow) * 32 + fk];
#pragma unroll
      for (int i = 0; i < FI; i++)
#pragma unroll
        for (int j = 0; j < FJ; j++) {
          if (HALF_OUT)
            acc[i][j] = __builtin_amdgcn_mfma_f32_16x16x32_f16(bf[j], af[i], acc[i][j], 0, 0, 0);
          else
            acc[i][j] = __builtin_amdgcn_mfma_f32_16x16x32_f16(af[i], bf[j], acc[i][j], 0, 0, 0);
        }
    }
    __syncthreads();
  }

  if (HALF_OUT) {
    _Float16* C = (_Float16*)Cv;
    const int mloc = lane & 15;
    const int nloc = (lane >> 4) * 4;
#pragma unroll
    for (int j = 0; j < FJ; j++) {
      const int gcol = bn + wc * (BN / 2) + j * 16 + nloc;
      float4 bj = *(const float4*)(bias + gcol);
#pragma unroll
      for (int i = 0; i < FI; i++) {
        const int grow = bm + wr * (BM / 2) + i * 16 + mloc;
        half4 hv;
        hv[0] = (_Float16)(acc[i][j][0] + bj.x);
        hv[1] = (_Float16)(acc[i][j][1] + bj.y);
        hv[2] = (_Float16)(acc[i][j][2] + bj.z);
        hv[3] = (_Float16)(acc[i][j][3] + bj.w);
        *(half4*)(C + (size_t)grow * N + gcol) = hv;
      }
    }
  } else {
    float* C = (float*)Cv;
    const int crow = (lane >> 4) * 4;
    const int ccol = lane & 15;
#pragma unroll
    for (int j = 0; j < FJ; j++) {
      const int gcol = bn + wc * (BN / 2) + j * 16 + ccol;
      const float bj = bias[gcol];
#pragma unroll
      for (int i = 0; i < FI; i++) {
        const int grow = bm + wr * (BM / 2) + i * 16 + crow;
        float* cp = C + (size_t)grow * N + gcol;
#pragma unroll
        for (int r = 0; r < 4; r++)
          cp[(size_t)r * N] = acc[i][j][r] + bj;
      }
    }
  }
}

// Quad-cooperative gathered attention, LDS-transpose reduction.
// Load pattern unchanged from measured-best (4 rows x 128B per instruction).
// Score partials kept lane-local (fdot2 chain); ONE LDS transpose replaces
// the 16 per-pass butterflies; lane r then owns score[r] -> 1 exp/lane,
// 6-step softmax butterflies; p redistributed to V layout via LDS broadcast.
__global__ __launch_bounds__(256)
void attn_kernel(const _Float16* __restrict__ qkv,
                 const int* __restrict__ routes,
                 _Float16* __restrict__ ao) {
  const int lane = threadIdx.x & 63;
  const int w    = threadIdx.x >> 6;
  const int g    = lane >> 4;          // row group 0..3
  const int c    = lane & 15;          // 8B chunk within row

  const int i    = blockIdx.x;          // 0..16383
  const int xcd  = i & 7;
  const int j    = i >> 3;
  const int bh   = j >> 6;
  const int qsub = j & 63;
  const int qblk = xcd * 64 + qsub;
  const int q    = qblk * 4 + w;
  const int h    = bh & 15;
  const int b    = bh >> 4;

  // stride 68 keeps float4 reads 16B-aligned; read conflicts ~4-way (1 op/wave)
  __shared__ float scratch[4][16 * 68];
  float* sw = scratch[w];

  const size_t row_base = (size_t)b * SEQ;
  const int    hoff     = h * HEAD_DIM;

  // routes via direct L1 loads (same 256B line for the whole wave)
  const int* rbase = routes + q * K_NEI + g;
  int rq[16];
#pragma unroll
  for (int t = 0; t < 16; t++) rq[t] = rbase[4 * t];

  const half4 qv = *(const half4*)(qkv + (row_base + q) * QKV_DIM + hoff + 4 * c);
  const half2t qv01 = { qv[0], qv[1] };
  const half2t qv23 = { qv[2], qv[3] };

  half4 vv[16];

  // ---- score partials: pass t = row rq[t] (4 rows/instr), V parked ----
#pragma unroll
  for (int t = 0; t < 16; t++) {
    const _Float16* kp = qkv + (row_base + rq[t]) * QKV_DIM + DIM + hoff + 4 * c;
    half4 kv = *(const half4*)kp;
    vv[t]    = *(const half4*)(kp + DIM);
    half2t k01 = { kv[0], kv[1] };
    half2t k23 = { kv[2], kv[3] };
    float sp = dot2h(k23, qv23, dot2h(k01, qv01, 0.f));
    sw[t * 68 + lane] = sp;          // [t][lane], stride-1 -> conflict-free
  }

  // ---- transpose read: lane r sums the 16 chunk-partials of row r ----
  const int rb = (lane >> 2) * 68 + (lane & 3) * 16;
  float4 p0 = *(const float4*)&sw[rb];
  float4 p1 = *(const float4*)&sw[rb + 4];
  float4 p2 = *(const float4*)&sw[rb + 8];
  float4 p3 = *(const float4*)&sw[rb + 12];
  float sc = ((p0.x + p0.y) + (p0.z + p0.w)) + ((p1.x + p1.y) + (p1.z + p1.w))
           + ((p2.x + p2.y) + (p2.z + p2.w)) + ((p3.x + p3.y) + (p3.z + p3.w));

  // ---- softmax over 64 lanes (1 score per lane) ----
  float m = sc;
#pragma unroll
  for (int off = 1; off < 64; off <<= 1) m = fmaxf(m, __shfl_xor(m, off));
  float e = __expf((sc - m) * ATT_SCALE);
  float sum = e;
#pragma unroll
  for (int off = 1; off < 64; off <<= 1) sum += __shfl_xor(sum, off);
  const float pn = e / sum;

  // ---- redistribute p to V layout (in-order DS per wave => safe reuse) ----
  sw[lane] = pn;
  float o0 = 0.f, o1 = 0.f, o2 = 0.f, o3 = 0.f;
#pragma unroll
  for (int t = 0; t < 16; t++) {
    const float p = sw[4 * t + g];   // 16-lane same-address broadcast
    o0 += p * (float)vv[t][0];
    o1 += p * (float)vv[t][1];
    o2 += p * (float)vv[t][2];
    o3 += p * (float)vv[t][3];
  }
  o0 += __shfl_xor(o0, 16); o0 += __shfl_xor(o0, 32);
  o1 += __shfl_xor(o1, 16); o1 += __shfl_xor(o1, 32);
  o2 += __shfl_xor(o2, 16); o2 += __shfl_xor(o2, 32);
  o3 += __shfl_xor(o3, 16); o3 += __shfl_xor(o3, 32);

  if (g == 0) {
    half4 hv;
    hv[0] = (_Float16)o0; hv[1] = (_Float16)o1;
    hv[2] = (_Float16)o2; hv[3] = (_Float16)o3;
    *(half4*)(ao + (row_base + q) * DIM + hoff + 4 * c) = hv;
  }
}

extern "C" void kernel_launch(void* const* d_in, const int* in_sizes, int n_in,
                              void* d_out, int out_size, void* d_ws, size_t ws_size,
                              hipStream_t stream) {
  const float* x      = (const float*)d_in[0];
  const int*   routes = (const int*)  d_in[1];
  const float* qkv_w  = (const float*)d_in[2];
  const float* qkv_b  = (const float*)d_in[3];
  const float* out_w  = (const float*)d_in[4];
  const float* out_b  = (const float*)d_in[5];
  float* out = (float*)d_out;

  _Float16* qkvh = (_Float16*)d_ws;                       // 4096*3072
  _Float16* aoh  = qkvh + (size_t)MROWS * QKV_DIM;        // 4096*1024
  _Float16* xh   = aoh  + (size_t)MROWS * DIM;            // 4096*1024
  _Float16* wh   = xh   + (size_t)MROWS * DIM;            // 3072*1024
  _Float16* owh  = wh   + (size_t)QKV_DIM * DIM;          // 1024*1024

  cast3<<<1024, 256, 0, stream>>>(x, MROWS * DIM / 4,
                                  qkv_w, QKV_DIM * DIM / 4,
                                  out_w, DIM * DIM / 4,
                                  xh, wh, owh);

  // QKV projection: 128x128 tile, 768 blocks
  {
    dim3 g(QKV_DIM / 128, MROWS / 128);
    gemm_bt_f16<128, 128, true><<<g, 256, 0, stream>>>(xh, wh, qkv_b, qkvh,
                                                       MROWS, QKV_DIM, DIM);
  }

  attn_kernel<<<(BATCH * HEADS * SEQ) / 4, 256, 0, stream>>>(qkvh, routes, aoh);

  // output projection: 64x128 tile -> 512 blocks
  {
    dim3 g(DIM / 128, MROWS / 64);
    gemm_bt_f16<64, 128, false><<<g, 256, 0, stream>>>(aoh, owh, out_b, out,
                                                       MROWS, DIM, DIM);
  }
}